// Round 3
// baseline (4024.988 us; speedup 1.0000x reference)
//
#include <hip/hip_runtime.h>

// EpisodicMemoryModule: B=128, T=512, U=256, EMB=256, 3 memory hops.
// Round 3: scan -> 4 waves x 64 cols (halves LDS A-fragment traffic),
// u-axis storage permutation so each lane's tile-pair outputs are adjacent
// (conflict-free b32 LDS writes, b64 x-loads). Weights carry the permutation.

#define DEVI static __device__ __forceinline__

typedef float f32x4 __attribute__((ext_vector_type(4)));
typedef unsigned short u16x8 __attribute__((ext_vector_type(8)));
typedef __bf16 bf16x8 __attribute__((ext_vector_type(8)));

DEVI f32x4 mfma16(u16x8 a, u16x8 b, f32x4 c) {
  return __builtin_amdgcn_mfma_f32_16x16x32_bf16(
      __builtin_bit_cast(bf16x8, a), __builtin_bit_cast(bf16x8, b), c, 0, 0, 0);
}
DEVI float bf2f(unsigned short u) {
  unsigned int x = ((unsigned int)u) << 16;
  return __builtin_bit_cast(float, x);
}
DEVI float lo2f(unsigned int u) {
  unsigned int x = u << 16;
  return __builtin_bit_cast(float, x);
}
DEVI float hi2f(unsigned int u) {
  unsigned int x = u & 0xffff0000u;
  return __builtin_bit_cast(float, x);
}
DEVI unsigned short f2bf(float f) {
  unsigned int u = __builtin_bit_cast(unsigned int, f);
  return (unsigned short)((u + 0x7fffu + ((u >> 16) & 1u)) >> 16);
}
DEVI unsigned int cvtpk(float lo, float hi) {  // [bf16(lo) | bf16(hi)<<16] RTNE
  unsigned int r;
  asm("v_cvt_pk_bf16_f32 %0, %1, %2" : "=v"(r) : "v"(lo), "v"(hi));
  return r;
}
DEVI float sigmoid_f(float x) {  // inf-safe: rcp(inf)=0
  float e = __expf(-x);
  return __builtin_amdgcn_rcpf(1.f + e);
}
DEVI float tanh_f(float x) {
  float xc = fmaxf(x, -12.f);
  float e = __expf(-2.f * xc);
  return (1.f - e) * __builtin_amdgcn_rcpf(1.f + e);
}
// u-axis storage permutation: storage s <- logical c
// s(c) = 32*(c>>5) + 2*(c&15) + ((c>>4)&1); inverse below.
DEVI int invperm(int s) { return 32 * (s >> 5) + 16 * (s & 1) + ((s & 31) >> 1); }

// ---------------- prep kernels ----------------

__global__ void cast_facts_kernel(const float* __restrict__ in,
                                  unsigned short* __restrict__ out, int n8) {
  int i = blockIdx.x * blockDim.x + threadIdx.x;
  int stride = gridDim.x * blockDim.x;
  for (; i < n8; i += stride) {
    const float4* p = (const float4*)(in + (size_t)i * 8);
    float4 a = p[0], b = p[1];
    u16x8 o;
    o[0] = f2bf(a.x); o[1] = f2bf(a.y); o[2] = f2bf(a.z); o[3] = f2bf(a.w);
    o[4] = f2bf(b.x); o[5] = f2bf(b.y); o[6] = f2bf(b.z); o[7] = f2bf(b.w);
    *(u16x8*)(out + (size_t)i * 8) = o;
  }
}

// z=0/1: wrT/whT[storage_v][k]   = W[k][inv(sv)]      (+ permuted biases at r==0)
// z=2/3: urT/uhT[storage_v][storage_k] = U[inv(sk)][inv(sv)]
// z=4/5: l1qT/l1mT (unpermuted, EMB axis)
__global__ void prep_weights_kernel(const float* __restrict__ Wr,
                                    const float* __restrict__ Wh,
                                    const float* __restrict__ Ur,
                                    const float* __restrict__ Uh,
                                    const float* __restrict__ l1W,
                                    const float* __restrict__ br,
                                    const float* __restrict__ bh,
                                    unsigned short* __restrict__ wrT,
                                    unsigned short* __restrict__ whT,
                                    unsigned short* __restrict__ urT,
                                    unsigned short* __restrict__ uhT,
                                    unsigned short* __restrict__ l1qT,
                                    unsigned short* __restrict__ l1mT,
                                    float* __restrict__ brP,
                                    float* __restrict__ bhP) {
  int z = blockIdx.y;
  int r = blockIdx.x;   // output row (storage index for z<4)
  int c = threadIdx.x;  // 0..255
  if (z < 2) {
    const float* src = (z == 0) ? Wr : Wh;
    unsigned short* dst = (z == 0) ? wrT : whT;
    dst[r * 256 + c] = f2bf(src[c * 256 + invperm(r)]);
    if (r == 0) {
      if (z == 0) brP[c] = br[invperm(c)];
      else        bhP[c] = bh[invperm(c)];
    }
  } else if (z < 4) {
    const float* src = (z == 2) ? Ur : Uh;
    unsigned short* dst = (z == 2) ? urT : uhT;
    dst[r * 256 + c] = f2bf(src[invperm(c) * 256 + invperm(r)]);
  } else {
    unsigned short* dst = (z == 4) ? l1qT : l1mT;
    for (int kk = c; kk < 512; kk += 256) {
      int srow;
      if (z == 4) srow = (kk < 256) ? kk : (kk + 256);
      else        srow = (kk < 256) ? (kk + 256) : (kk + 512);
      dst[r * 512 + kk] = f2bf(l1W[srow * 256 + r]);
    }
  }
}

__global__ void init_qm_kernel(const float* __restrict__ question,
                               unsigned short* __restrict__ qbf,
                               unsigned short* __restrict__ mbf,
                               float* __restrict__ memory) {
  int i = blockIdx.x * 256 + threadIdx.x;  // 32768
  float v = question[i];
  unsigned short u = f2bf(v);
  qbf[i] = u;
  mbf[i] = u;
  memory[i] = v;
}

// ---------------- xr/xh GEMM (writes interleaved [T][B][2U], storage cols) ----
__global__ __launch_bounds__(256, 2) void gemm_xrxh_kernel(
    const unsigned short* __restrict__ factsb,
    const unsigned short* __restrict__ wrT,
    const unsigned short* __restrict__ whT,
    const float* __restrict__ brP, const float* __restrict__ bhP,
    unsigned short* __restrict__ xrxh) {
  const int b = blockIdx.x >> 3;
  const int t0 = (blockIdx.x & 7) * 64;
  const int w = threadIdx.x >> 6, l = threadIdx.x & 63;
  const int l15 = l & 15, lg = l >> 4;
  const int koff = lg * 8;
  const int m0 = t0 + w * 16;

  f32x4 accR[16], accH[16];
  const f32x4 zz = {0.f, 0.f, 0.f, 0.f};
#pragma unroll
  for (int nt = 0; nt < 16; nt++) { accR[nt] = zz; accH[nt] = zz; }

  const unsigned short* arow = factsb + ((size_t)b * 512 + (m0 + l15)) * 256;
#pragma unroll
  for (int ks = 0; ks < 8; ks++) {
    u16x8 a = *(const u16x8*)&arow[ks * 32 + koff];
#pragma unroll
    for (int nt = 0; nt < 16; nt++) {
      u16x8 bwr = *(const u16x8*)&wrT[(size_t)(nt * 16 + l15) * 256 + ks * 32 + koff];
      u16x8 bwh = *(const u16x8*)&whT[(size_t)(nt * 16 + l15) * 256 + ks * 32 + koff];
      accR[nt] = mfma16(a, bwr, accR[nt]);
      accH[nt] = mfma16(a, bwh, accH[nt]);
    }
  }
#pragma unroll
  for (int nt = 0; nt < 16; nt++) {
    const int col = nt * 16 + l15;  // storage col
    const float bvr = brP[col], bvh = bhP[col];
#pragma unroll
    for (int r = 0; r < 4; r++) {
      const int t = m0 + lg * 4 + r;
      unsigned int pk = cvtpk(accR[nt][r] + bvr, accH[nt][r] + bvh);
      *(unsigned int*)&xrxh[((size_t)t * 128 + b) * 512 + col * 2] = pk;
    }
  }
}

// ---------------- attention scores GEMM (K=1024 fused transforms) ----------------
__global__ __launch_bounds__(256, 2) void scores_kernel(
    const unsigned short* __restrict__ factsb,
    const unsigned short* __restrict__ l1qT,
    const unsigned short* __restrict__ l1mT,
    const float* __restrict__ l1b,
    const unsigned short* __restrict__ qbf,
    const unsigned short* __restrict__ mbf,
    const float* __restrict__ l2w, float* __restrict__ scores) {
  const int b = blockIdx.x >> 3;
  const int t0 = (blockIdx.x & 7) * 64;
  const int w = threadIdx.x >> 6, l = threadIdx.x & 63;
  const int l15 = l & 15, lg = l >> 4;
  const int koff = lg * 8;
  const int m0 = t0 + w * 16;

  u16x8 mvq[8], mvm[8];
#pragma unroll
  for (int s = 0; s < 8; s++) {
    mvq[s] = *(const u16x8*)&qbf[b * 256 + s * 32 + koff];
    mvm[s] = *(const u16x8*)&mbf[b * 256 + s * 32 + koff];
  }

  f32x4 acc[16];
  const f32x4 zz = {0.f, 0.f, 0.f, 0.f};
#pragma unroll
  for (int nt = 0; nt < 16; nt++) acc[nt] = zz;

  const unsigned short* arow = factsb + ((size_t)b * 512 + (m0 + l15)) * 256;

  for (int q2 = 0; q2 < 4; q2++) {  // 0 f*q(W1) 1 f*m(W2) 2 |f-q|(W3) 3 |f-m|(W4)
    const unsigned short* WTs = (q2 & 1) ? l1mT : l1qT;
    const int bko = (q2 >> 1) * 256;
    const bool isabs = (q2 >= 2);
#pragma unroll
    for (int kss = 0; kss < 8; kss++) {
      u16x8 f = *(const u16x8*)&arow[kss * 32 + koff];
      u16x8 vv = (q2 & 1) ? mvm[kss] : mvq[kss];
      u16x8 a;
#pragma unroll
      for (int j = 0; j < 8; j++) {
        float fv = bf2f(f[j]), qv = bf2f(vv[j]);
        float rr = isabs ? fabsf(fv - qv) : fv * qv;
        a[j] = f2bf(rr);
      }
#pragma unroll
      for (int nt = 0; nt < 16; nt++) {
        u16x8 bb = *(const u16x8*)&WTs[(size_t)(nt * 16 + l15) * 512 + bko + kss * 32 + koff];
        acc[nt] = mfma16(a, bb, acc[nt]);
      }
    }
  }

  float part[4] = {0.f, 0.f, 0.f, 0.f};
#pragma unroll
  for (int nt = 0; nt < 16; nt++) {
    const int col = nt * 16 + l15;
    const float lw = l2w[col];
    const float bv = l1b[col];
#pragma unroll
    for (int r = 0; r < 4; r++) part[r] += tanh_f(acc[nt][r] + bv) * lw;
  }
#pragma unroll
  for (int m = 1; m < 16; m <<= 1) {
#pragma unroll
    for (int r = 0; r < 4; r++) part[r] += __shfl_xor(part[r], m, 64);
  }
  if (l15 == 0) {
#pragma unroll
    for (int r = 0; r < 4; r++)
      scores[(size_t)b * 512 + m0 + lg * 4 + r] = part[r];  // l2_b: softmax-invariant
  }
}

// ---------------- softmax over T per batch ----------------
__global__ void softmax_kernel(const float* __restrict__ scores,
                               float* __restrict__ att) {
  int b = blockIdx.x;
  int l = threadIdx.x;  // 64 threads, 8 scores each
  float v[8];
#pragma unroll
  for (int i = 0; i < 8; i++) v[i] = scores[b * 512 + l * 8 + i];
  float mx = v[0];
#pragma unroll
  for (int i = 1; i < 8; i++) mx = fmaxf(mx, v[i]);
#pragma unroll
  for (int m = 1; m < 64; m <<= 1) mx = fmaxf(mx, __shfl_xor(mx, m, 64));
  float s = 0.f;
#pragma unroll
  for (int i = 0; i < 8; i++) { v[i] = __expf(v[i] - mx); s += v[i]; }
#pragma unroll
  for (int m = 1; m < 64; m <<= 1) s += __shfl_xor(s, m, 64);
  float inv = __builtin_amdgcn_rcpf(s);
#pragma unroll
  for (int i = 0; i < 8; i++) att[(l * 8 + i) * 128 + b] = v[i] * inv;
}

// ---------------- attention-GRU scan ----------------
// 8 blocks x 256 threads (4 waves). Block = 16 batches; wave w owns storage cols
// [64w, 64w+64) as 4 N-tiles (2 adjacent pairs). Ur/Uh fragments fully in VGPRs
// (~256). h in LDS bf16. Tile pair outputs are storage-adjacent -> b32 writes
// (conflict-free), b64 x-loads. 1-step register prefetch of xr/xh/att.
struct PF {
  uint2 x[2][4];  // [pair][r]: .x = (xr|xh<<16) parity0, .y = parity1
  f32x4 g;
};

__global__ __launch_bounds__(256, 1) void scan_kernel(
    const unsigned short* __restrict__ xrxh,  // [T][B][2U] bf16, storage order
    const float* __restrict__ att,            // [T][B]
    const unsigned short* __restrict__ urT,   // [sv][sk] bf16 (both axes storage)
    const unsigned short* __restrict__ uhT,
    float* __restrict__ episode)              // [B][U] f32, logical order
{
  constexpr int PAD = 264;  // elements; 528B row stride
  __shared__ unsigned short hlds[16 * PAD];
  __shared__ unsigned short rhlds[16 * PAD];
  const int w = threadIdx.x >> 6, l = threadIdx.x & 63;
  const int l15 = l & 15, lg = l >> 4;
  const int koff = lg * 8;
  const int b0 = blockIdx.x * 16;
  const int lb = lg * 4;

  // tiles i = 2*p + q: storage col sc = 32*(2w+p) + 2*l15 + q
  u16x8 urf[4][8], uhf[4][8];
#pragma unroll
  for (int i = 0; i < 4; i++) {
    const int sc = 32 * (2 * w + (i >> 1)) + 2 * l15 + (i & 1);
#pragma unroll
    for (int ks = 0; ks < 8; ks++) {
      urf[i][ks] = *(const u16x8*)&urT[sc * 256 + ks * 32 + koff];
      uhf[i][ks] = *(const u16x8*)&uhT[sc * 256 + ks * 32 + koff];
    }
  }
  for (int i = threadIdx.x; i < 16 * PAD; i += 256) hlds[i] = 0;
  __syncthreads();

  const int hread = l15 * PAD + koff;
  int wdw[2][4], ro[2][4];
#pragma unroll
  for (int p = 0; p < 2; p++)
#pragma unroll
    for (int r = 0; r < 4; r++) {
      const int scp = 32 * (2 * w + p) + 2 * l15;
      wdw[p][r] = ((lb + r) * PAD + scp) >> 1;              // dword index in LDS
      ro[p][r] = (b0 + lb + r) * 512 + 2 * scp;             // element index in xrxh[t]
    }
  const int attoff = b0 + lb;

  float hc[4][4];  // [tile][r]
#pragma unroll
  for (int i = 0; i < 4; i++)
#pragma unroll
    for (int r = 0; r < 4; r++) hc[i][r] = 0.f;

  const f32x4 zz = {0.f, 0.f, 0.f, 0.f};

  auto prefetch = [&](int t) {
    PF pf;
    const unsigned short* xb = xrxh + (size_t)t * 65536;
#pragma unroll
    for (int p = 0; p < 2; p++)
#pragma unroll
      for (int r = 0; r < 4; r++)
        pf.x[p][r] = *(const uint2*)&xb[ro[p][r]];
    pf.g = *(const f32x4*)&att[t * 128 + attoff];
    return pf;
  };

  auto step = [&](const PF& pf) {
    u16x8 hf[8];
#pragma unroll
    for (int ks = 0; ks < 8; ks++)
      hf[ks] = *(const u16x8*)&hlds[hread + ks * 32];
    f32x4 aA[4], aB[4];
#pragma unroll
    for (int i = 0; i < 4; i++) { aA[i] = zz; aB[i] = zz; }
#pragma unroll
    for (int ks = 0; ks < 4; ks++)
#pragma unroll
      for (int i = 0; i < 4; i++) {
        aA[i] = mfma16(hf[ks], urf[i][ks], aA[i]);
        aB[i] = mfma16(hf[ks + 4], urf[i][ks + 4], aB[i]);
      }
#pragma unroll
    for (int r = 0; r < 4; r++)
#pragma unroll
      for (int p = 0; p < 2; p++) {
        const uint2 xv = pf.x[p][r];
        const int i0 = 2 * p, i1 = 2 * p + 1;
        float s0 = aA[i0][r] + aB[i0][r] + lo2f(xv.x);
        float s1 = aA[i1][r] + aB[i1][r] + lo2f(xv.y);
        float rh0 = sigmoid_f(s0) * hc[i0][r];
        float rh1 = sigmoid_f(s1) * hc[i1][r];
        ((unsigned int*)rhlds)[wdw[p][r]] = cvtpk(rh0, rh1);
      }
    __syncthreads();
    u16x8 rf[8];
#pragma unroll
    for (int ks = 0; ks < 8; ks++)
      rf[ks] = *(const u16x8*)&rhlds[hread + ks * 32];
#pragma unroll
    for (int i = 0; i < 4; i++) { aA[i] = zz; aB[i] = zz; }
#pragma unroll
    for (int ks = 0; ks < 4; ks++)
#pragma unroll
      for (int i = 0; i < 4; i++) {
        aA[i] = mfma16(rf[ks], uhf[i][ks], aA[i]);
        aB[i] = mfma16(rf[ks + 4], uhf[i][ks + 4], aB[i]);
      }
#pragma unroll
    for (int r = 0; r < 4; r++)
#pragma unroll
      for (int p = 0; p < 2; p++) {
        const uint2 xv = pf.x[p][r];
        const int i0 = 2 * p, i1 = 2 * p + 1;
        float ht0 = tanh_f(aA[i0][r] + aB[i0][r] + hi2f(xv.x));
        float ht1 = tanh_f(aA[i1][r] + aB[i1][r] + hi2f(xv.y));
        const float g = pf.g[r];
        hc[i0][r] = fmaf(g, ht0 - hc[i0][r], hc[i0][r]);
        hc[i1][r] = fmaf(g, ht1 - hc[i1][r], hc[i1][r]);
        ((unsigned int*)hlds)[wdw[p][r]] = cvtpk(hc[i0][r], hc[i1][r]);
      }
    __syncthreads();
  };

  PF cur = prefetch(0);
#pragma unroll 2
  for (int t = 0; t < 512; t++) {
    PF nxt = prefetch(t + 1);  // t=511 reads adjacent ws (allocated, unused)
    step(cur);
    cur = nxt;
  }
  // episode in logical order: inv(sc) = 32*(2w+p) + 16*q + l15
#pragma unroll
  for (int i = 0; i < 4; i++) {
    const int lcol = 32 * (2 * w + (i >> 1)) + 16 * (i & 1) + l15;
#pragma unroll
    for (int r = 0; r < 4; r++)
      episode[(size_t)(b0 + lb + r) * 256 + lcol] = hc[i][r];
  }
}

// ---------------- memory update ----------------
__global__ __launch_bounds__(256) void memupd_kernel(
    const float* __restrict__ episode, const float* __restrict__ question,
    const float* __restrict__ memW, const float* __restrict__ memb,
    float* __restrict__ memory, unsigned short* __restrict__ mbf) {
  __shared__ float cat[768];
  int b = blockIdx.x, v = threadIdx.x;
  cat[v] = memory[b * 256 + v];
  cat[256 + v] = episode[b * 256 + v];
  cat[512 + v] = question[b * 256 + v];
  __syncthreads();
  float acc = memb[v];
#pragma unroll 8
  for (int u = 0; u < 768; u++) acc += cat[u] * memW[u * 256 + v];
  acc = fmaxf(acc, 0.f);
  memory[b * 256 + v] = acc;
  mbf[b * 256 + v] = f2bf(acc);
}

__global__ void writeout_kernel(const float* __restrict__ memory,
                                const float* __restrict__ question,
                                float* __restrict__ out) {
  int i = blockIdx.x * 256 + threadIdx.x;  // 65536
  int b = i >> 9, c = i & 511;
  out[i] = (c < 256) ? memory[b * 256 + c] : question[b * 256 + (c - 256)];
}

// ---------------- launch ----------------
extern "C" void kernel_launch(void* const* d_in, const int* in_sizes, int n_in,
                              void* d_out, int out_size, void* d_ws, size_t ws_size,
                              hipStream_t stream) {
  (void)in_sizes; (void)n_in; (void)out_size; (void)ws_size;
  const float* facts = (const float*)d_in[0];
  const float* question = (const float*)d_in[1];
  const float* l1W = (const float*)d_in[2];
  const float* l1b = (const float*)d_in[3];
  const float* l2W = (const float*)d_in[4];
  const float* Wr = (const float*)d_in[6];
  const float* Ur = (const float*)d_in[7];
  const float* br = (const float*)d_in[8];
  const float* Wh = (const float*)d_in[9];
  const float* Uh = (const float*)d_in[10];
  const float* bh = (const float*)d_in[11];
  const float* memW = (const float*)d_in[12];
  const float* memb = (const float*)d_in[13];
  float* out = (float*)d_out;

  char* ws = (char*)d_ws;
  unsigned short* factsb = (unsigned short*)(ws + 0);          // 33,554,432 B
  unsigned short* xrxh   = (unsigned short*)(ws + 33554432);   // 67,108,864 B [T][B][2U]
  unsigned short* wrT    = (unsigned short*)(ws + 100663296);  // 131,072 B
  unsigned short* whT    = (unsigned short*)(ws + 100794368);
  unsigned short* urT    = (unsigned short*)(ws + 100925440);
  unsigned short* uhT    = (unsigned short*)(ws + 101056512);
  unsigned short* l1qT   = (unsigned short*)(ws + 101187584);  // 524,288 B
  unsigned short* l1mT   = (unsigned short*)(ws + 101711872);  // 524,288 B
  unsigned short* qbf    = (unsigned short*)(ws + 102236160);  // 65,536 B
  unsigned short* mbf    = (unsigned short*)(ws + 102301696);  // 65,536 B
  float* scores          = (float*)(ws + 102367232);           // 262,144 B
  float* att             = (float*)(ws + 102629376);           // 262,144 B
  float* memory          = (float*)(ws + 102891520);           // 131,072 B
  float* episode         = (float*)(ws + 103022592);           // 131,072 B
  float* brP             = (float*)(ws + 103153664);           // 1,024 B
  float* bhP             = (float*)(ws + 103154688);           // 1,024 B

  cast_facts_kernel<<<2048, 256, 0, stream>>>(facts, factsb, 2097152);
  prep_weights_kernel<<<dim3(256, 6), 256, 0, stream>>>(
      Wr, Wh, Ur, Uh, l1W, br, bh, wrT, whT, urT, uhT, l1qT, l1mT, brP, bhP);
  init_qm_kernel<<<128, 256, 0, stream>>>(question, qbf, mbf, memory);

  gemm_xrxh_kernel<<<1024, 256, 0, stream>>>(factsb, wrT, whT, brP, bhP, xrxh);

  for (int step = 0; step < 3; step++) {
    scores_kernel<<<1024, 256, 0, stream>>>(factsb, l1qT, l1mT, l1b, qbf, mbf, l2W, scores);
    softmax_kernel<<<128, 64, 0, stream>>>(scores, att);
    scan_kernel<<<8, 256, 0, stream>>>(xrxh, att, urT, uhT, episode);
    memupd_kernel<<<128, 256, 0, stream>>>(episode, question, memW, memb, memory, mbf);
  }
  writeout_kernel<<<256, 256, 0, stream>>>(memory, question, out);
}

// Round 4
// 2963.656 us; speedup vs baseline: 1.3581x; 1.3581x over previous
//
#include <hip/hip_runtime.h>

// EpisodicMemoryModule: B=128, T=512, U=256, EMB=256, 3 memory hops.
// Round 4: scan = R2's 8-wave structure (2 waves/SIMD overlap — R3's 4-wave
// regression traced to 1 wave/SIMD exposing all chain stalls) + R3's u-axis
// storage permutation (paired conflict-free b32 LDS writes, uint2 x-loads).
// Scores: A-transform built in shifted-f32 domain + cvt_pk packing.

#define DEVI static __device__ __forceinline__

typedef float f32x4 __attribute__((ext_vector_type(4)));
typedef unsigned short u16x8 __attribute__((ext_vector_type(8)));
typedef unsigned int u32x4 __attribute__((ext_vector_type(4)));
typedef __bf16 bf16x8 __attribute__((ext_vector_type(8)));

DEVI f32x4 mfma16(u16x8 a, u16x8 b, f32x4 c) {
  return __builtin_amdgcn_mfma_f32_16x16x32_bf16(
      __builtin_bit_cast(bf16x8, a), __builtin_bit_cast(bf16x8, b), c, 0, 0, 0);
}
DEVI float bf2f(unsigned short u) {
  unsigned int x = ((unsigned int)u) << 16;
  return __builtin_bit_cast(float, x);
}
DEVI float lo2f(unsigned int u) {
  unsigned int x = u << 16;
  return __builtin_bit_cast(float, x);
}
DEVI float hi2f(unsigned int u) {
  unsigned int x = u & 0xffff0000u;
  return __builtin_bit_cast(float, x);
}
DEVI unsigned short f2bf(float f) {
  unsigned int u = __builtin_bit_cast(unsigned int, f);
  return (unsigned short)((u + 0x7fffu + ((u >> 16) & 1u)) >> 16);
}
DEVI unsigned int cvtpk(float lo, float hi) {  // [bf16(lo) | bf16(hi)<<16] RTNE
  unsigned int r;
  asm("v_cvt_pk_bf16_f32 %0, %1, %2" : "=v"(r) : "v"(lo), "v"(hi));
  return r;
}
DEVI float sigmoid_f(float x) {  // inf-safe: rcp(inf)=0
  float e = __expf(-x);
  return __builtin_amdgcn_rcpf(1.f + e);
}
DEVI float tanh_f(float x) {
  float xc = fmaxf(x, -12.f);
  float e = __expf(-2.f * xc);
  return (1.f - e) * __builtin_amdgcn_rcpf(1.f + e);
}
// u-axis storage permutation: s(c) = 32*(c>>5) + 2*(c&15) + ((c>>4)&1)
DEVI int invperm(int s) { return 32 * (s >> 5) + 16 * (s & 1) + ((s & 31) >> 1); }

// ---------------- prep kernels ----------------

__global__ void cast_facts_kernel(const float* __restrict__ in,
                                  unsigned short* __restrict__ out, int n8) {
  int i = blockIdx.x * blockDim.x + threadIdx.x;
  int stride = gridDim.x * blockDim.x;
  for (; i < n8; i += stride) {
    const float4* p = (const float4*)(in + (size_t)i * 8);
    float4 a = p[0], b = p[1];
    u16x8 o;
    o[0] = f2bf(a.x); o[1] = f2bf(a.y); o[2] = f2bf(a.z); o[3] = f2bf(a.w);
    o[4] = f2bf(b.x); o[5] = f2bf(b.y); o[6] = f2bf(b.z); o[7] = f2bf(b.w);
    *(u16x8*)(out + (size_t)i * 8) = o;
  }
}

// z=0/1: wrT/whT[storage_v][k] = W[k][inv(sv)]  (+ permuted biases at r==0)
// z=2/3: urT/uhT[storage_v][storage_k] = U[inv(sk)][inv(sv)]
// z=4/5: l1qT/l1mT (unpermuted, EMB axis)
__global__ void prep_weights_kernel(const float* __restrict__ Wr,
                                    const float* __restrict__ Wh,
                                    const float* __restrict__ Ur,
                                    const float* __restrict__ Uh,
                                    const float* __restrict__ l1W,
                                    const float* __restrict__ br,
                                    const float* __restrict__ bh,
                                    unsigned short* __restrict__ wrT,
                                    unsigned short* __restrict__ whT,
                                    unsigned short* __restrict__ urT,
                                    unsigned short* __restrict__ uhT,
                                    unsigned short* __restrict__ l1qT,
                                    unsigned short* __restrict__ l1mT,
                                    float* __restrict__ brP,
                                    float* __restrict__ bhP) {
  int z = blockIdx.y;
  int r = blockIdx.x;   // output row (storage index for z<4)
  int c = threadIdx.x;  // 0..255
  if (z < 2) {
    const float* src = (z == 0) ? Wr : Wh;
    unsigned short* dst = (z == 0) ? wrT : whT;
    dst[r * 256 + c] = f2bf(src[c * 256 + invperm(r)]);
    if (r == 0) {
      if (z == 0) brP[c] = br[invperm(c)];
      else        bhP[c] = bh[invperm(c)];
    }
  } else if (z < 4) {
    const float* src = (z == 2) ? Ur : Uh;
    unsigned short* dst = (z == 2) ? urT : uhT;
    dst[r * 256 + c] = f2bf(src[invperm(c) * 256 + invperm(r)]);
  } else {
    unsigned short* dst = (z == 4) ? l1qT : l1mT;
    for (int kk = c; kk < 512; kk += 256) {
      int srow;
      if (z == 4) srow = (kk < 256) ? kk : (kk + 256);
      else        srow = (kk < 256) ? (kk + 256) : (kk + 512);
      dst[r * 512 + kk] = f2bf(l1W[srow * 256 + r]);
    }
  }
}

__global__ void init_qm_kernel(const float* __restrict__ question,
                               unsigned short* __restrict__ qbf,
                               unsigned short* __restrict__ mbf,
                               float* __restrict__ memory) {
  int i = blockIdx.x * 256 + threadIdx.x;  // 32768
  float v = question[i];
  unsigned short u = f2bf(v);
  qbf[i] = u;
  mbf[i] = u;
  memory[i] = v;
}

// ---------------- xr/xh GEMM (writes interleaved [T][B][2U], storage cols) ----
__global__ __launch_bounds__(256, 2) void gemm_xrxh_kernel(
    const unsigned short* __restrict__ factsb,
    const unsigned short* __restrict__ wrT,
    const unsigned short* __restrict__ whT,
    const float* __restrict__ brP, const float* __restrict__ bhP,
    unsigned short* __restrict__ xrxh) {
  const int b = blockIdx.x >> 3;
  const int t0 = (blockIdx.x & 7) * 64;
  const int w = threadIdx.x >> 6, l = threadIdx.x & 63;
  const int l15 = l & 15, lg = l >> 4;
  const int koff = lg * 8;
  const int m0 = t0 + w * 16;

  f32x4 accR[16], accH[16];
  const f32x4 zz = {0.f, 0.f, 0.f, 0.f};
#pragma unroll
  for (int nt = 0; nt < 16; nt++) { accR[nt] = zz; accH[nt] = zz; }

  const unsigned short* arow = factsb + ((size_t)b * 512 + (m0 + l15)) * 256;
#pragma unroll
  for (int ks = 0; ks < 8; ks++) {
    u16x8 a = *(const u16x8*)&arow[ks * 32 + koff];
#pragma unroll
    for (int nt = 0; nt < 16; nt++) {
      u16x8 bwr = *(const u16x8*)&wrT[(size_t)(nt * 16 + l15) * 256 + ks * 32 + koff];
      u16x8 bwh = *(const u16x8*)&whT[(size_t)(nt * 16 + l15) * 256 + ks * 32 + koff];
      accR[nt] = mfma16(a, bwr, accR[nt]);
      accH[nt] = mfma16(a, bwh, accH[nt]);
    }
  }
#pragma unroll
  for (int nt = 0; nt < 16; nt++) {
    const int col = nt * 16 + l15;  // storage col
    const float bvr = brP[col], bvh = bhP[col];
#pragma unroll
    for (int r = 0; r < 4; r++) {
      const int t = m0 + lg * 4 + r;
      unsigned int pk = cvtpk(accR[nt][r] + bvr, accH[nt][r] + bvh);
      *(unsigned int*)&xrxh[((size_t)t * 128 + b) * 512 + col * 2] = pk;
    }
  }
}

// ---------------- attention scores GEMM (K=1024 fused transforms) ----------------
__global__ __launch_bounds__(256, 2) void scores_kernel(
    const unsigned short* __restrict__ factsb,
    const unsigned short* __restrict__ l1qT,
    const unsigned short* __restrict__ l1mT,
    const float* __restrict__ l1b,
    const unsigned short* __restrict__ qbf,
    const unsigned short* __restrict__ mbf,
    const float* __restrict__ l2w, float* __restrict__ scores) {
  const int b = blockIdx.x >> 3;
  const int t0 = (blockIdx.x & 7) * 64;
  const int w = threadIdx.x >> 6, l = threadIdx.x & 63;
  const int l15 = l & 15, lg = l >> 4;
  const int koff = lg * 8;
  const int m0 = t0 + w * 16;

  u32x4 mvq[8], mvm[8];
#pragma unroll
  for (int s = 0; s < 8; s++) {
    mvq[s] = *(const u32x4*)&qbf[b * 256 + s * 32 + koff];
    mvm[s] = *(const u32x4*)&mbf[b * 256 + s * 32 + koff];
  }

  f32x4 acc[16];
  const f32x4 zz = {0.f, 0.f, 0.f, 0.f};
#pragma unroll
  for (int nt = 0; nt < 16; nt++) acc[nt] = zz;

  const unsigned short* arow = factsb + ((size_t)b * 512 + (m0 + l15)) * 256;

  for (int q2 = 0; q2 < 4; q2++) {  // 0 f*q(W1) 1 f*m(W2) 2 |f-q|(W3) 3 |f-m|(W4)
    const unsigned short* WTs = (q2 & 1) ? l1mT : l1qT;
    const int bko = (q2 >> 1) * 256;
    const bool isabs = (q2 >= 2);
#pragma unroll
    for (int kss = 0; kss < 8; kss++) {
      u32x4 f = *(const u32x4*)&arow[kss * 32 + koff];
      u32x4 vv = (q2 & 1) ? mvm[kss] : mvq[kss];
      u32x4 a;
#pragma unroll
      for (int j = 0; j < 4; j++) {  // shifted-f32 domain: bf16<<16 is exact f32
        float fl = lo2f(f[j]), fh = hi2f(f[j]);
        float vl = lo2f(vv[j]), vh = hi2f(vv[j]);
        if (isabs) a[j] = cvtpk(fl - vl, fh - vh) & 0x7fff7fffu;
        else       a[j] = cvtpk(fl * vl, fh * vh);
      }
      u16x8 ab = __builtin_bit_cast(u16x8, a);
#pragma unroll
      for (int nt = 0; nt < 16; nt++) {
        u16x8 bb = *(const u16x8*)&WTs[(size_t)(nt * 16 + l15) * 512 + bko + kss * 32 + koff];
        acc[nt] = mfma16(ab, bb, acc[nt]);
      }
    }
  }

  float part[4] = {0.f, 0.f, 0.f, 0.f};
#pragma unroll
  for (int nt = 0; nt < 16; nt++) {
    const int col = nt * 16 + l15;
    const float lw = l2w[col];
    const float bv = l1b[col];
#pragma unroll
    for (int r = 0; r < 4; r++) part[r] += tanh_f(acc[nt][r] + bv) * lw;
  }
#pragma unroll
  for (int m = 1; m < 16; m <<= 1) {
#pragma unroll
    for (int r = 0; r < 4; r++) part[r] += __shfl_xor(part[r], m, 64);
  }
  if (l15 == 0) {
#pragma unroll
    for (int r = 0; r < 4; r++)
      scores[(size_t)b * 512 + m0 + lg * 4 + r] = part[r];  // l2_b: softmax-invariant
  }
}

// ---------------- softmax over T per batch ----------------
__global__ void softmax_kernel(const float* __restrict__ scores,
                               float* __restrict__ att) {
  int b = blockIdx.x;
  int l = threadIdx.x;  // 64 threads, 8 scores each
  float v[8];
#pragma unroll
  for (int i = 0; i < 8; i++) v[i] = scores[b * 512 + l * 8 + i];
  float mx = v[0];
#pragma unroll
  for (int i = 1; i < 8; i++) mx = fmaxf(mx, v[i]);
#pragma unroll
  for (int m = 1; m < 64; m <<= 1) mx = fmaxf(mx, __shfl_xor(mx, m, 64));
  float s = 0.f;
#pragma unroll
  for (int i = 0; i < 8; i++) { v[i] = __expf(v[i] - mx); s += v[i]; }
#pragma unroll
  for (int m = 1; m < 64; m <<= 1) s += __shfl_xor(s, m, 64);
  float inv = __builtin_amdgcn_rcpf(s);
#pragma unroll
  for (int i = 0; i < 8; i++) att[(l * 8 + i) * 128 + b] = v[i] * inv;
}

// ---------------- attention-GRU scan ----------------
// 8 blocks x 512 threads (8 waves = 2/SIMD). Block = 16 batches; wave w owns
// storage cols [32w, 32w+32) as an adjacent tile pair (q=0,1). Ur/Uh fragments
// in registers (32 frags -> AGPR file). h in LDS bf16. Paired b32 LDS writes
// (conflict-free via storage permutation), uint2 x-loads, 1-step prefetch.
struct PF {
  uint2 x[4];  // [r]: .x = (xr|xh<<16) for q=0 col, .y = for q=1 col
  f32x4 g;
};

__global__ __launch_bounds__(512, 2) void scan_kernel(
    const unsigned short* __restrict__ xrxh,  // [T][B][2U] bf16, storage order
    const float* __restrict__ att,            // [T][B]
    const unsigned short* __restrict__ urT,   // [sv][sk] bf16 (both axes storage)
    const unsigned short* __restrict__ uhT,
    float* __restrict__ episode)              // [B][U] f32, logical order
{
  constexpr int PAD = 264;  // elements; 528B row stride
  __shared__ unsigned short hlds[16 * PAD];
  __shared__ unsigned short rhlds[16 * PAD];
  const int w = threadIdx.x >> 6, l = threadIdx.x & 63;
  const int l15 = l & 15, lg = l >> 4;
  const int koff = lg * 8;
  const int b0 = blockIdx.x * 16;
  const int lb = lg * 4;

  // tiles q=0,1: storage col sc = 32w + 2*l15 + q
  u16x8 urf[2][8], uhf[2][8];
#pragma unroll
  for (int q = 0; q < 2; q++) {
    const int sc = 32 * w + 2 * l15 + q;
#pragma unroll
    for (int ks = 0; ks < 8; ks++) {
      urf[q][ks] = *(const u16x8*)&urT[sc * 256 + ks * 32 + koff];
      uhf[q][ks] = *(const u16x8*)&uhT[sc * 256 + ks * 32 + koff];
    }
  }
  for (int i = threadIdx.x; i < 16 * PAD; i += 512) hlds[i] = 0;
  __syncthreads();

  const int hread = l15 * PAD + koff;
  int wdw[4], ro[4];
#pragma unroll
  for (int r = 0; r < 4; r++) {
    wdw[r] = (lb + r) * (PAD / 2) + 16 * w + l15;        // dword index in LDS
    ro[r] = (b0 + lb + r) * 512 + 64 * w + 4 * l15;      // element index in xrxh[t]
  }
  const int attoff = b0 + lb;

  float hc[2][4];
#pragma unroll
  for (int q = 0; q < 2; q++)
#pragma unroll
    for (int r = 0; r < 4; r++) hc[q][r] = 0.f;

  const f32x4 zz = {0.f, 0.f, 0.f, 0.f};

  auto prefetch = [&](int t) {
    PF pf;
    const unsigned short* xb = xrxh + (size_t)t * 65536;
#pragma unroll
    for (int r = 0; r < 4; r++) pf.x[r] = *(const uint2*)&xb[ro[r]];
    pf.g = *(const f32x4*)&att[t * 128 + attoff];
    return pf;
  };

  auto step = [&](const PF& pf) {
    u16x8 hf[8];
#pragma unroll
    for (int ks = 0; ks < 8; ks++)
      hf[ks] = *(const u16x8*)&hlds[hread + ks * 32];
    f32x4 aA[2] = {zz, zz}, aB[2] = {zz, zz};
#pragma unroll
    for (int ks = 0; ks < 4; ks++)
#pragma unroll
      for (int q = 0; q < 2; q++) {
        aA[q] = mfma16(hf[ks], urf[q][ks], aA[q]);
        aB[q] = mfma16(hf[ks + 4], urf[q][ks + 4], aB[q]);
      }
#pragma unroll
    for (int r = 0; r < 4; r++) {
      const uint2 xv = pf.x[r];
      float s0 = aA[0][r] + aB[0][r] + lo2f(xv.x);
      float s1 = aA[1][r] + aB[1][r] + lo2f(xv.y);
      float rh0 = sigmoid_f(s0) * hc[0][r];
      float rh1 = sigmoid_f(s1) * hc[1][r];
      ((unsigned int*)rhlds)[wdw[r]] = cvtpk(rh0, rh1);
    }
    __syncthreads();
    u16x8 rf[8];
#pragma unroll
    for (int ks = 0; ks < 8; ks++)
      rf[ks] = *(const u16x8*)&rhlds[hread + ks * 32];
    f32x4 bA[2] = {zz, zz}, bB[2] = {zz, zz};
#pragma unroll
    for (int ks = 0; ks < 4; ks++)
#pragma unroll
      for (int q = 0; q < 2; q++) {
        bA[q] = mfma16(rf[ks], uhf[q][ks], bA[q]);
        bB[q] = mfma16(rf[ks + 4], uhf[q][ks + 4], bB[q]);
      }
#pragma unroll
    for (int r = 0; r < 4; r++) {
      const uint2 xv = pf.x[r];
      float ht0 = tanh_f(bA[0][r] + bB[0][r] + hi2f(xv.x));
      float ht1 = tanh_f(bA[1][r] + bB[1][r] + hi2f(xv.y));
      const float g = pf.g[r];
      hc[0][r] = fmaf(g, ht0 - hc[0][r], hc[0][r]);
      hc[1][r] = fmaf(g, ht1 - hc[1][r], hc[1][r]);
      ((unsigned int*)hlds)[wdw[r]] = cvtpk(hc[0][r], hc[1][r]);
    }
    __syncthreads();
  };

  PF cur = prefetch(0);
#pragma unroll 2
  for (int t = 0; t < 512; t++) {
    PF nxt = prefetch(t + 1);  // t=511 reads adjacent ws (allocated, unused)
    step(cur);
    cur = nxt;
  }
  // episode in logical order: inv(sc) = 32w + 16q + l15
#pragma unroll
  for (int q = 0; q < 2; q++) {
    const int lcol = 32 * w + 16 * q + l15;
#pragma unroll
    for (int r = 0; r < 4; r++)
      episode[(size_t)(b0 + lb + r) * 256 + lcol] = hc[q][r];
  }
}

// ---------------- memory update ----------------
__global__ __launch_bounds__(256) void memupd_kernel(
    const float* __restrict__ episode, const float* __restrict__ question,
    const float* __restrict__ memW, const float* __restrict__ memb,
    float* __restrict__ memory, unsigned short* __restrict__ mbf) {
  __shared__ float cat[768];
  int b = blockIdx.x, v = threadIdx.x;
  cat[v] = memory[b * 256 + v];
  cat[256 + v] = episode[b * 256 + v];
  cat[512 + v] = question[b * 256 + v];
  __syncthreads();
  float acc = memb[v];
#pragma unroll 8
  for (int u = 0; u < 768; u++) acc += cat[u] * memW[u * 256 + v];
  acc = fmaxf(acc, 0.f);
  memory[b * 256 + v] = acc;
  mbf[b * 256 + v] = f2bf(acc);
}

__global__ void writeout_kernel(const float* __restrict__ memory,
                                const float* __restrict__ question,
                                float* __restrict__ out) {
  int i = blockIdx.x * 256 + threadIdx.x;  // 65536
  int b = i >> 9, c = i & 511;
  out[i] = (c < 256) ? memory[b * 256 + c] : question[b * 256 + (c - 256)];
}

// ---------------- launch ----------------
extern "C" void kernel_launch(void* const* d_in, const int* in_sizes, int n_in,
                              void* d_out, int out_size, void* d_ws, size_t ws_size,
                              hipStream_t stream) {
  (void)in_sizes; (void)n_in; (void)out_size; (void)ws_size;
  const float* facts = (const float*)d_in[0];
  const float* question = (const float*)d_in[1];
  const float* l1W = (const float*)d_in[2];
  const float* l1b = (const float*)d_in[3];
  const float* l2W = (const float*)d_in[4];
  const float* Wr = (const float*)d_in[6];
  const float* Ur = (const float*)d_in[7];
  const float* br = (const float*)d_in[8];
  const float* Wh = (const float*)d_in[9];
  const float* Uh = (const float*)d_in[10];
  const float* bh = (const float*)d_in[11];
  const float* memW = (const float*)d_in[12];
  const float* memb = (const float*)d_in[13];
  float* out = (float*)d_out;

  char* ws = (char*)d_ws;
  unsigned short* factsb = (unsigned short*)(ws + 0);          // 33,554,432 B
  unsigned short* xrxh   = (unsigned short*)(ws + 33554432);   // 67,108,864 B [T][B][2U]
  unsigned short* wrT    = (unsigned short*)(ws + 100663296);  // 131,072 B
  unsigned short* whT    = (unsigned short*)(ws + 100794368);
  unsigned short* urT    = (unsigned short*)(ws + 100925440);
  unsigned short* uhT    = (unsigned short*)(ws + 101056512);
  unsigned short* l1qT   = (unsigned short*)(ws + 101187584);  // 524,288 B
  unsigned short* l1mT   = (unsigned short*)(ws + 101711872);  // 524,288 B
  unsigned short* qbf    = (unsigned short*)(ws + 102236160);  // 65,536 B
  unsigned short* mbf    = (unsigned short*)(ws + 102301696);  // 65,536 B
  float* scores          = (float*)(ws + 102367232);           // 262,144 B
  float* att             = (float*)(ws + 102629376);           // 262,144 B
  float* memory          = (float*)(ws + 102891520);           // 131,072 B
  float* episode         = (float*)(ws + 103022592);           // 131,072 B
  float* brP             = (float*)(ws + 103153664);           // 1,024 B
  float* bhP             = (float*)(ws + 103154688);           // 1,024 B

  cast_facts_kernel<<<2048, 256, 0, stream>>>(facts, factsb, 2097152);
  prep_weights_kernel<<<dim3(256, 6), 256, 0, stream>>>(
      Wr, Wh, Ur, Uh, l1W, br, bh, wrT, whT, urT, uhT, l1qT, l1mT, brP, bhP);
  init_qm_kernel<<<128, 256, 0, stream>>>(question, qbf, mbf, memory);

  gemm_xrxh_kernel<<<1024, 256, 0, stream>>>(factsb, wrT, whT, brP, bhP, xrxh);

  for (int step = 0; step < 3; step++) {
    scores_kernel<<<1024, 256, 0, stream>>>(factsb, l1qT, l1mT, l1b, qbf, mbf, l2W, scores);
    softmax_kernel<<<128, 64, 0, stream>>>(scores, att);
    scan_kernel<<<8, 512, 0, stream>>>(xrxh, att, urT, uhT, episode);
    memupd_kernel<<<128, 256, 0, stream>>>(episode, question, memW, memb, memory, mbf);
  }
  writeout_kernel<<<256, 256, 0, stream>>>(memory, question, out);
}

// Round 5
// 2496.238 us; speedup vs baseline: 1.6124x; 1.1872x over previous
//
#include <hip/hip_runtime.h>

// EpisodicMemoryModule: B=128, T=512, U=256, EMB=256, 3 memory hops.
// Round 5: scores -> M=32/wave (2 t-tiles per B-fragment, 2:1 MFMA:load);
// memupd fused into scan epilogue (cat staged in LDS, MFMA vs prepped memWT).
// Scan core unchanged from R4 (626 us, near structural floor).

#define DEVI static __device__ __forceinline__

typedef float f32x4 __attribute__((ext_vector_type(4)));
typedef unsigned short u16x8 __attribute__((ext_vector_type(8)));
typedef unsigned int u32x4 __attribute__((ext_vector_type(4)));
typedef __bf16 bf16x8 __attribute__((ext_vector_type(8)));

DEVI f32x4 mfma16(u16x8 a, u16x8 b, f32x4 c) {
  return __builtin_amdgcn_mfma_f32_16x16x32_bf16(
      __builtin_bit_cast(bf16x8, a), __builtin_bit_cast(bf16x8, b), c, 0, 0, 0);
}
DEVI float bf2f(unsigned short u) {
  unsigned int x = ((unsigned int)u) << 16;
  return __builtin_bit_cast(float, x);
}
DEVI float lo2f(unsigned int u) {
  unsigned int x = u << 16;
  return __builtin_bit_cast(float, x);
}
DEVI float hi2f(unsigned int u) {
  unsigned int x = u & 0xffff0000u;
  return __builtin_bit_cast(float, x);
}
DEVI unsigned short f2bf(float f) {
  unsigned int u = __builtin_bit_cast(unsigned int, f);
  return (unsigned short)((u + 0x7fffu + ((u >> 16) & 1u)) >> 16);
}
DEVI unsigned int cvtpk(float lo, float hi) {  // [bf16(lo) | bf16(hi)<<16] RTNE
  unsigned int r;
  asm("v_cvt_pk_bf16_f32 %0, %1, %2" : "=v"(r) : "v"(lo), "v"(hi));
  return r;
}
DEVI float sigmoid_f(float x) {  // inf-safe: rcp(inf)=0
  float e = __expf(-x);
  return __builtin_amdgcn_rcpf(1.f + e);
}
DEVI float tanh_f(float x) {
  float xc = fmaxf(x, -12.f);
  float e = __expf(-2.f * xc);
  return (1.f - e) * __builtin_amdgcn_rcpf(1.f + e);
}
// u-axis storage permutation: s(c) = 32*(c>>5) + 2*(c&15) + ((c>>4)&1)
DEVI int invperm(int s) { return 32 * (s >> 5) + 16 * (s & 1) + ((s & 31) >> 1); }

// ---------------- prep kernels ----------------

__global__ void cast_facts_kernel(const float* __restrict__ in,
                                  unsigned short* __restrict__ out, int n8) {
  int i = blockIdx.x * blockDim.x + threadIdx.x;
  int stride = gridDim.x * blockDim.x;
  for (; i < n8; i += stride) {
    const float4* p = (const float4*)(in + (size_t)i * 8);
    float4 a = p[0], b = p[1];
    u16x8 o;
    o[0] = f2bf(a.x); o[1] = f2bf(a.y); o[2] = f2bf(a.z); o[3] = f2bf(a.w);
    o[4] = f2bf(b.x); o[5] = f2bf(b.y); o[6] = f2bf(b.z); o[7] = f2bf(b.w);
    *(u16x8*)(out + (size_t)i * 8) = o;
  }
}

// z=0/1: wrT/whT[sv][k] = W[k][inv(sv)]  (+ permuted biases at r==0)
// z=2/3: urT/uhT[sv][sk] = U[inv(sk)][inv(sv)]
// z=4/5: l1qT/l1mT (unpermuted, EMB axis)
// z=6:   memWT[v][k] (768 k; episode segment rows permuted to match scan layout)
__global__ void prep_weights_kernel(const float* __restrict__ Wr,
                                    const float* __restrict__ Wh,
                                    const float* __restrict__ Ur,
                                    const float* __restrict__ Uh,
                                    const float* __restrict__ l1W,
                                    const float* __restrict__ br,
                                    const float* __restrict__ bh,
                                    const float* __restrict__ memW,
                                    unsigned short* __restrict__ wrT,
                                    unsigned short* __restrict__ whT,
                                    unsigned short* __restrict__ urT,
                                    unsigned short* __restrict__ uhT,
                                    unsigned short* __restrict__ l1qT,
                                    unsigned short* __restrict__ l1mT,
                                    unsigned short* __restrict__ memWT,
                                    float* __restrict__ brP,
                                    float* __restrict__ bhP) {
  int z = blockIdx.y;
  int r = blockIdx.x;   // output row (storage index for z<4, logical v for z==6)
  int c = threadIdx.x;  // 0..255
  if (z < 2) {
    const float* src = (z == 0) ? Wr : Wh;
    unsigned short* dst = (z == 0) ? wrT : whT;
    dst[r * 256 + c] = f2bf(src[c * 256 + invperm(r)]);
    if (r == 0) {
      if (z == 0) brP[c] = br[invperm(c)];
      else        bhP[c] = bh[invperm(c)];
    }
  } else if (z < 4) {
    const float* src = (z == 2) ? Ur : Uh;
    unsigned short* dst = (z == 2) ? urT : uhT;
    dst[r * 256 + c] = f2bf(src[invperm(c) * 256 + invperm(r)]);
  } else if (z < 6) {
    unsigned short* dst = (z == 4) ? l1qT : l1mT;
    for (int kk = c; kk < 512; kk += 256) {
      int srow;
      if (z == 4) srow = (kk < 256) ? kk : (kk + 256);
      else        srow = (kk < 256) ? (kk + 256) : (kk + 512);
      dst[r * 512 + kk] = f2bf(l1W[srow * 256 + r]);
    }
  } else {  // z == 6
    for (int kk = c; kk < 768; kk += 256) {
      int ksrc = (kk < 256) ? kk : (kk < 512 ? 256 + invperm(kk - 256) : kk);
      memWT[r * 768 + kk] = f2bf(memW[ksrc * 256 + r]);
    }
  }
}

__global__ void init_qm_kernel(const float* __restrict__ question,
                               unsigned short* __restrict__ qbf,
                               unsigned short* __restrict__ mbf) {
  int i = blockIdx.x * 256 + threadIdx.x;  // 32768
  unsigned short u = f2bf(question[i]);
  qbf[i] = u;
  mbf[i] = u;
}

// ---------------- xr/xh GEMM (writes interleaved [T][B][2U], storage cols) ----
__global__ __launch_bounds__(256, 2) void gemm_xrxh_kernel(
    const unsigned short* __restrict__ factsb,
    const unsigned short* __restrict__ wrT,
    const unsigned short* __restrict__ whT,
    const float* __restrict__ brP, const float* __restrict__ bhP,
    unsigned short* __restrict__ xrxh) {
  const int b = blockIdx.x >> 3;
  const int t0 = (blockIdx.x & 7) * 64;
  const int w = threadIdx.x >> 6, l = threadIdx.x & 63;
  const int l15 = l & 15, lg = l >> 4;
  const int koff = lg * 8;
  const int m0 = t0 + w * 16;

  f32x4 accR[16], accH[16];
  const f32x4 zz = {0.f, 0.f, 0.f, 0.f};
#pragma unroll
  for (int nt = 0; nt < 16; nt++) { accR[nt] = zz; accH[nt] = zz; }

  const unsigned short* arow = factsb + ((size_t)b * 512 + (m0 + l15)) * 256;
#pragma unroll
  for (int ks = 0; ks < 8; ks++) {
    u16x8 a = *(const u16x8*)&arow[ks * 32 + koff];
#pragma unroll
    for (int nt = 0; nt < 16; nt++) {
      u16x8 bwr = *(const u16x8*)&wrT[(size_t)(nt * 16 + l15) * 256 + ks * 32 + koff];
      u16x8 bwh = *(const u16x8*)&whT[(size_t)(nt * 16 + l15) * 256 + ks * 32 + koff];
      accR[nt] = mfma16(a, bwr, accR[nt]);
      accH[nt] = mfma16(a, bwh, accH[nt]);
    }
  }
#pragma unroll
  for (int nt = 0; nt < 16; nt++) {
    const int col = nt * 16 + l15;  // storage col
    const float bvr = brP[col], bvh = bhP[col];
#pragma unroll
    for (int r = 0; r < 4; r++) {
      const int t = m0 + lg * 4 + r;
      unsigned int pk = cvtpk(accR[nt][r] + bvr, accH[nt][r] + bvh);
      *(unsigned int*)&xrxh[((size_t)t * 128 + b) * 512 + col * 2] = pk;
    }
  }
}

// ---------------- attention scores GEMM (K=1024 fused transforms, M=32/wave) --
__global__ __launch_bounds__(256, 2) void scores_kernel(
    const unsigned short* __restrict__ factsb,
    const unsigned short* __restrict__ l1qT,
    const unsigned short* __restrict__ l1mT,
    const float* __restrict__ l1b,
    const unsigned short* __restrict__ qbf,
    const unsigned short* __restrict__ mbf,
    const float* __restrict__ l2w, float* __restrict__ scores) {
  const int b = blockIdx.x >> 2;
  const int t0 = (blockIdx.x & 2) * 64;        // 0 or 128... (see below)
  const int half = blockIdx.x & 1;             // fine split for grid 512
  const int w = threadIdx.x >> 6, l = threadIdx.x & 63;
  const int l15 = l & 15, lg = l >> 4;
  const int koff = lg * 8;
  // block covers 128 t-rows: [tbase, tbase+128); wave w tiles at +16w and +64+16w
  const int tbase = (blockIdx.x & 3) * 128;
  (void)t0; (void)half;
  const int m0 = tbase + w * 16;

  f32x4 acc[2][16];
  const f32x4 zz = {0.f, 0.f, 0.f, 0.f};
#pragma unroll
  for (int s = 0; s < 2; s++)
#pragma unroll
    for (int nt = 0; nt < 16; nt++) acc[s][nt] = zz;

  const unsigned short* arow0 = factsb + ((size_t)b * 512 + (m0 + l15)) * 256;
  const unsigned short* arow1 = arow0 + 64 * 256;
  const unsigned short* qv = qbf + b * 256;
  const unsigned short* mv = mbf + b * 256;

  for (int q2 = 0; q2 < 4; q2++) {  // 0 f*q(W1) 1 f*m(W2) 2 |f-q|(W3) 3 |f-m|(W4)
    const unsigned short* WTs = (q2 & 1) ? l1mT : l1qT;
    const unsigned short* vvp = (q2 & 1) ? mv : qv;
    const int bko = (q2 >> 1) * 256;
    const bool isabs = (q2 >= 2);
#pragma unroll
    for (int kss = 0; kss < 8; kss++) {
      u32x4 f0 = *(const u32x4*)&arow0[kss * 32 + koff];
      u32x4 f1 = *(const u32x4*)&arow1[kss * 32 + koff];
      u32x4 vv = *(const u32x4*)&vvp[kss * 32 + koff];
      u32x4 a0, a1;
#pragma unroll
      for (int j = 0; j < 4; j++) {  // shifted-f32 domain: bf16<<16 is exact f32
        float vl = lo2f(vv[j]), vh = hi2f(vv[j]);
        if (isabs) {
          a0[j] = cvtpk(lo2f(f0[j]) - vl, hi2f(f0[j]) - vh) & 0x7fff7fffu;
          a1[j] = cvtpk(lo2f(f1[j]) - vl, hi2f(f1[j]) - vh) & 0x7fff7fffu;
        } else {
          a0[j] = cvtpk(lo2f(f0[j]) * vl, hi2f(f0[j]) * vh);
          a1[j] = cvtpk(lo2f(f1[j]) * vl, hi2f(f1[j]) * vh);
        }
      }
      u16x8 ab0 = __builtin_bit_cast(u16x8, a0);
      u16x8 ab1 = __builtin_bit_cast(u16x8, a1);
#pragma unroll
      for (int nt = 0; nt < 16; nt++) {
        u16x8 bb = *(const u16x8*)&WTs[(size_t)(nt * 16 + l15) * 512 + bko + kss * 32 + koff];
        acc[0][nt] = mfma16(ab0, bb, acc[0][nt]);
        acc[1][nt] = mfma16(ab1, bb, acc[1][nt]);
      }
    }
  }

  float part[2][4] = {{0.f, 0.f, 0.f, 0.f}, {0.f, 0.f, 0.f, 0.f}};
#pragma unroll
  for (int nt = 0; nt < 16; nt++) {
    const int col = nt * 16 + l15;
    const float lw = l2w[col];
    const float bv = l1b[col];
#pragma unroll
    for (int s = 0; s < 2; s++)
#pragma unroll
      for (int r = 0; r < 4; r++) part[s][r] += tanh_f(acc[s][nt][r] + bv) * lw;
  }
#pragma unroll
  for (int m = 1; m < 16; m <<= 1)
#pragma unroll
    for (int s = 0; s < 2; s++)
#pragma unroll
      for (int r = 0; r < 4; r++) part[s][r] += __shfl_xor(part[s][r], m, 64);
  if (l15 == 0) {
#pragma unroll
    for (int s = 0; s < 2; s++)
#pragma unroll
      for (int r = 0; r < 4; r++)
        scores[(size_t)b * 512 + m0 + s * 64 + lg * 4 + r] = part[s][r];
  }
}

// ---------------- softmax over T per batch ----------------
__global__ void softmax_kernel(const float* __restrict__ scores,
                               float* __restrict__ att) {
  int b = blockIdx.x;
  int l = threadIdx.x;  // 64 threads, 8 scores each
  float v[8];
#pragma unroll
  for (int i = 0; i < 8; i++) v[i] = scores[b * 512 + l * 8 + i];
  float mx = v[0];
#pragma unroll
  for (int i = 1; i < 8; i++) mx = fmaxf(mx, v[i]);
#pragma unroll
  for (int m = 1; m < 64; m <<= 1) mx = fmaxf(mx, __shfl_xor(mx, m, 64));
  float s = 0.f;
#pragma unroll
  for (int i = 0; i < 8; i++) { v[i] = __expf(v[i] - mx); s += v[i]; }
#pragma unroll
  for (int m = 1; m < 64; m <<= 1) s += __shfl_xor(s, m, 64);
  float inv = __builtin_amdgcn_rcpf(s);
#pragma unroll
  for (int i = 0; i < 8; i++) att[(l * 8 + i) * 128 + b] = v[i] * inv;
}

// ---------------- attention-GRU scan + fused memory update ----------------
// 8 blocks x 512 threads (8 waves = 2/SIMD). Block = 16 batches; wave w owns
// storage cols [32w, 32w+32) as an adjacent tile pair (q=0,1). Ur/Uh fragments
// in registers. h in LDS bf16. Paired b32 LDS writes, uint2 x-loads, 1-step
// prefetch. Epilogue: memory = relu([mem|episode|question] @ memW + memb).
struct PF {
  uint2 x[4];  // [r]: .x = (xr|xh<<16) for q=0 col, .y = for q=1 col
  f32x4 g;
};

__global__ __launch_bounds__(512, 2) void scan_kernel(
    const unsigned short* __restrict__ xrxh,   // [T][B][2U] bf16, storage order
    const float* __restrict__ att,             // [T][B]
    const unsigned short* __restrict__ urT,    // [sv][sk] bf16
    const unsigned short* __restrict__ uhT,
    const unsigned short* __restrict__ memWT,  // [v][768] bf16 (episode rows permuted)
    const float* __restrict__ memb,
    const unsigned short* __restrict__ qbf,
    unsigned short* __restrict__ mbf,          // read old memory, write new
    float* __restrict__ memory)                // write new memory f32
{
  constexpr int PAD = 264;   // elements; 528B row stride
  constexpr int CPAD = 776;  // cat row stride (768+8)
  __shared__ unsigned short hlds[16 * PAD];
  __shared__ unsigned short rhlds[16 * PAD];
  __shared__ unsigned short cat[16 * CPAD];
  const int w = threadIdx.x >> 6, l = threadIdx.x & 63;
  const int l15 = l & 15, lg = l >> 4;
  const int koff = lg * 8;
  const int b0 = blockIdx.x * 16;
  const int lb = lg * 4;

  // tiles q=0,1: storage col sc = 32w + 2*l15 + q
  u16x8 urf[2][8], uhf[2][8];
#pragma unroll
  for (int q = 0; q < 2; q++) {
    const int sc = 32 * w + 2 * l15 + q;
#pragma unroll
    for (int ks = 0; ks < 8; ks++) {
      urf[q][ks] = *(const u16x8*)&urT[sc * 256 + ks * 32 + koff];
      uhf[q][ks] = *(const u16x8*)&uhT[sc * 256 + ks * 32 + koff];
    }
  }
  for (int i = threadIdx.x; i < 16 * PAD; i += 512) hlds[i] = 0;
  __syncthreads();

  const int hread = l15 * PAD + koff;
  int wdw[4], ro[4];
#pragma unroll
  for (int r = 0; r < 4; r++) {
    wdw[r] = (lb + r) * (PAD / 2) + 16 * w + l15;    // dword index in LDS
    ro[r] = (b0 + lb + r) * 512 + 64 * w + 4 * l15;  // element index in xrxh[t]
  }
  const int attoff = b0 + lb;

  float hc[2][4];
#pragma unroll
  for (int q = 0; q < 2; q++)
#pragma unroll
    for (int r = 0; r < 4; r++) hc[q][r] = 0.f;

  const f32x4 zz = {0.f, 0.f, 0.f, 0.f};

  auto prefetch = [&](int t) {
    PF pf;
    const unsigned short* xb = xrxh + (size_t)t * 65536;
#pragma unroll
    for (int r = 0; r < 4; r++) pf.x[r] = *(const uint2*)&xb[ro[r]];
    pf.g = *(const f32x4*)&att[t * 128 + attoff];
    return pf;
  };

  auto step = [&](const PF& pf) {
    u16x8 hf[8];
#pragma unroll
    for (int ks = 0; ks < 8; ks++)
      hf[ks] = *(const u16x8*)&hlds[hread + ks * 32];
    f32x4 aA[2] = {zz, zz}, aB[2] = {zz, zz};
#pragma unroll
    for (int ks = 0; ks < 4; ks++)
#pragma unroll
      for (int q = 0; q < 2; q++) {
        aA[q] = mfma16(hf[ks], urf[q][ks], aA[q]);
        aB[q] = mfma16(hf[ks + 4], urf[q][ks + 4], aB[q]);
      }
#pragma unroll
    for (int r = 0; r < 4; r++) {
      const uint2 xv = pf.x[r];
      float s0 = aA[0][r] + aB[0][r] + lo2f(xv.x);
      float s1 = aA[1][r] + aB[1][r] + lo2f(xv.y);
      float rh0 = sigmoid_f(s0) * hc[0][r];
      float rh1 = sigmoid_f(s1) * hc[1][r];
      ((unsigned int*)rhlds)[wdw[r]] = cvtpk(rh0, rh1);
    }
    __syncthreads();
    u16x8 rf[8];
#pragma unroll
    for (int ks = 0; ks < 8; ks++)
      rf[ks] = *(const u16x8*)&rhlds[hread + ks * 32];
    f32x4 bA[2] = {zz, zz}, bB[2] = {zz, zz};
#pragma unroll
    for (int ks = 0; ks < 4; ks++)
#pragma unroll
      for (int q = 0; q < 2; q++) {
        bA[q] = mfma16(rf[ks], uhf[q][ks], bA[q]);
        bB[q] = mfma16(rf[ks + 4], uhf[q][ks + 4], bB[q]);
      }
#pragma unroll
    for (int r = 0; r < 4; r++) {
      const uint2 xv = pf.x[r];
      float ht0 = tanh_f(bA[0][r] + bB[0][r] + hi2f(xv.x));
      float ht1 = tanh_f(bA[1][r] + bB[1][r] + hi2f(xv.y));
      const float g = pf.g[r];
      hc[0][r] = fmaf(g, ht0 - hc[0][r], hc[0][r]);
      hc[1][r] = fmaf(g, ht1 - hc[1][r], hc[1][r]);
      ((unsigned int*)hlds)[wdw[r]] = cvtpk(hc[0][r], hc[1][r]);
    }
    __syncthreads();
  };

  PF cur = prefetch(0);
#pragma unroll 2
  for (int t = 0; t < 512; t++) {
    PF nxt = prefetch(t + 1);  // t=511 reads adjacent ws (allocated, unused)
    step(cur);
    cur = nxt;
  }

  // ===== fused memory update =====
  // cat[16][CPAD]: [0:256) memory (logical), [256:512) episode (storage order),
  //                [512:768) question (logical)
  {
    const int i = (int)threadIdx.x;  // 512 threads: one u16x8 each for mem & q
    const int bb = i >> 5, cc = (i & 31) * 8;
    *(u16x8*)&cat[bb * CPAD + cc] = *(const u16x8*)&mbf[(b0 + bb) * 256 + cc];
    *(u16x8*)&cat[bb * CPAD + 512 + cc] = *(const u16x8*)&qbf[(b0 + bb) * 256 + cc];
  }
#pragma unroll
  for (int r = 0; r < 4; r++) {
    *(unsigned int*)&cat[(lb + r) * CPAD + 256 + 32 * w + 2 * l15] =
        cvtpk(hc[0][r], hc[1][r]);
  }
  __syncthreads();

  f32x4 mA[2] = {zz, zz}, mB[2] = {zz, zz};
#pragma unroll
  for (int ks = 0; ks < 24; ks += 2) {
    u16x8 a0 = *(const u16x8*)&cat[l15 * CPAD + ks * 32 + koff];
    u16x8 a1 = *(const u16x8*)&cat[l15 * CPAD + (ks + 1) * 32 + koff];
#pragma unroll
    for (int q = 0; q < 2; q++) {
      const int vrow = (2 * w + q) * 16 + l15;
      u16x8 bf0 = *(const u16x8*)&memWT[(size_t)vrow * 768 + ks * 32 + koff];
      u16x8 bf1 = *(const u16x8*)&memWT[(size_t)vrow * 768 + (ks + 1) * 32 + koff];
      mA[q] = mfma16(a0, bf0, mA[q]);
      mB[q] = mfma16(a1, bf1, mB[q]);
    }
  }
#pragma unroll
  for (int q = 0; q < 2; q++) {
    const int col = (2 * w + q) * 16 + l15;  // logical v
    const float bv = memb[col];
#pragma unroll
    for (int r = 0; r < 4; r++) {
      float v = fmaxf(mA[q][r] + mB[q][r] + bv, 0.f);
      memory[(size_t)(b0 + lb + r) * 256 + col] = v;
      mbf[(size_t)(b0 + lb + r) * 256 + col] = f2bf(v);
    }
  }
}

__global__ void writeout_kernel(const float* __restrict__ memory,
                                const float* __restrict__ question,
                                float* __restrict__ out) {
  int i = blockIdx.x * 256 + threadIdx.x;  // 65536
  int b = i >> 9, c = i & 511;
  out[i] = (c < 256) ? memory[b * 256 + c] : question[b * 256 + (c - 256)];
}

// ---------------- launch ----------------
extern "C" void kernel_launch(void* const* d_in, const int* in_sizes, int n_in,
                              void* d_out, int out_size, void* d_ws, size_t ws_size,
                              hipStream_t stream) {
  (void)in_sizes; (void)n_in; (void)out_size; (void)ws_size;
  const float* facts = (const float*)d_in[0];
  const float* question = (const float*)d_in[1];
  const float* l1W = (const float*)d_in[2];
  const float* l1b = (const float*)d_in[3];
  const float* l2W = (const float*)d_in[4];
  const float* Wr = (const float*)d_in[6];
  const float* Ur = (const float*)d_in[7];
  const float* br = (const float*)d_in[8];
  const float* Wh = (const float*)d_in[9];
  const float* Uh = (const float*)d_in[10];
  const float* bh = (const float*)d_in[11];
  const float* memW = (const float*)d_in[12];
  const float* memb = (const float*)d_in[13];
  float* out = (float*)d_out;

  char* ws = (char*)d_ws;
  unsigned short* factsb = (unsigned short*)(ws + 0);          // 33,554,432 B
  unsigned short* xrxh   = (unsigned short*)(ws + 33554432);   // 67,108,864 B [T][B][2U]
  unsigned short* wrT    = (unsigned short*)(ws + 100663296);  // 131,072 B
  unsigned short* whT    = (unsigned short*)(ws + 100794368);
  unsigned short* urT    = (unsigned short*)(ws + 100925440);
  unsigned short* uhT    = (unsigned short*)(ws + 101056512);
  unsigned short* l1qT   = (unsigned short*)(ws + 101187584);  // 524,288 B
  unsigned short* l1mT   = (unsigned short*)(ws + 101711872);  // 524,288 B
  unsigned short* qbf    = (unsigned short*)(ws + 102236160);  // 65,536 B
  unsigned short* mbf    = (unsigned short*)(ws + 102301696);  // 65,536 B
  float* scores          = (float*)(ws + 102367232);           // 262,144 B
  float* att             = (float*)(ws + 102629376);           // 262,144 B
  float* memory          = (float*)(ws + 102891520);           // 131,072 B
  float* brP             = (float*)(ws + 103022592);           // 1,024 B
  float* bhP             = (float*)(ws + 103023616);           // 1,024 B
  unsigned short* memWT  = (unsigned short*)(ws + 103024640);  // 393,216 B

  cast_facts_kernel<<<2048, 256, 0, stream>>>(facts, factsb, 2097152);
  prep_weights_kernel<<<dim3(256, 7), 256, 0, stream>>>(
      Wr, Wh, Ur, Uh, l1W, br, bh, memW,
      wrT, whT, urT, uhT, l1qT, l1mT, memWT, brP, bhP);
  init_qm_kernel<<<128, 256, 0, stream>>>(question, qbf, mbf);

  gemm_xrxh_kernel<<<1024, 256, 0, stream>>>(factsb, wrT, whT, brP, bhP, xrxh);

  for (int step = 0; step < 3; step++) {
    scores_kernel<<<512, 256, 0, stream>>>(factsb, l1qT, l1mT, l1b, qbf, mbf, l2W, scores);
    softmax_kernel<<<128, 64, 0, stream>>>(scores, att);
    scan_kernel<<<8, 512, 0, stream>>>(xrxh, att, urT, uhT, memWT, memb, qbf, mbf, memory);
  }
  writeout_kernel<<<256, 256, 0, stream>>>(memory, question, out);
}